// Round 5
// baseline (462.384 us; speedup 1.0000x reference)
//
#include <hip/hip_runtime.h>
#include <hip/hip_bf16.h>
#include <math.h>
#include <stdint.h>

#define NROWS 1000000
#define NCOLS 100
#define NBINS 20
#define NB    19       // bin boundaries
#define W     50000u   // rows per bin
#define NH    2049     // buckets: 0 = catch-all (<0.5), 1..2048 = [0.5,1) in 2^-12 steps
#define SUBN  4096     // fine buckets (low 12 mantissa bits)

// ---------- ws layout (dword offsets) ----------
#define HIST_DW    0u        // len 2052
#define SUBCNT_DW  2052u     // len 19*4096 = 77824
#define SUBC_DW    79876u    // len 77824 (f32 sums of conf)
#define SUBA_DW    157700u   // len 77824 (f32 sums of acc)
#define BINS_DW    235524u   // len 80 dw = 40 doubles (byte 942096, 8-aligned)
#define TICKET_DW  235604u   // len 2
#define ZERO_DW    235606u   // everything above zeroed by k0
#define PREF_DW    235608u   // len 2052
#define BND_DW     237660u   // len 20
#define CONF_DW    237696u   // len 1000000, 16B-aligned; sign bit = accuracy

__device__ __forceinline__ unsigned int bucket_of(unsigned int bits) {
    // bits = positive-f32 pattern. conf < 0.5 -> 0 (catch-all).
    if (bits < 0x3F000000u) return 0u;
    unsigned int t = (bits >> 12) - 258048u + 1u;   // 1..2048 for [0.5,1)
    return t > 2048u ? 2048u : t;
}

// ---------- K0: zero hist/subcnt/subc/suba/bins/ticket ----------
__global__ __launch_bounds__(256) void k0_zero(unsigned int* __restrict__ wd) {
    unsigned int i = blockIdx.x * 256 + threadIdx.x;
    if (i < ZERO_DW) wd[i] = 0u;
}

// ---------- K1: rowmax + fused LDS histogram + last-block scan/bounds ------
__global__ __launch_bounds__(256) void k1_rowmax(const float* __restrict__ x,
                                                 const int* __restrict__ labels,
                                                 float* __restrict__ conf,
                                                 unsigned int* __restrict__ hist,
                                                 unsigned int* __restrict__ prefix,
                                                 unsigned int* __restrict__ bnd,
                                                 unsigned int* __restrict__ ticket) {
    __shared__ unsigned int lh[NH];
    for (int i = threadIdx.x; i < NH; i += 256) lh[i] = 0u;
    __syncthreads();

    int gtid = blockIdx.x * 256 + threadIdx.x;
    int wave = gtid >> 6;
    int lane = threadIdx.x & 63;
    int half = lane >> 5;
    int l    = lane & 31;
    int nwaves = (gridDim.x * 256) >> 6;

    for (int rp = wave; rp < NROWS / 2; rp += nwaves) {
        int row = rp * 2 + half;
        const float4* r4 = reinterpret_cast<const float4*>(x + (size_t)row * NCOLS);
        float best = -1.0f;
        int bi = 999;
        if (l < 25) {
            float4 v = r4[l];
            best = v.x; bi = 4 * l;
            if (v.y > best) { best = v.y; bi = 4 * l + 1; }
            if (v.z > best) { best = v.z; bi = 4 * l + 2; }
            if (v.w > best) { best = v.w; bi = 4 * l + 3; }
        }
        #pragma unroll
        for (int mask = 16; mask >= 1; mask >>= 1) {
            float ov = __shfl_xor(best, mask);
            int   oi = __shfl_xor(bi,   mask);
            if (ov > best || (ov == best && oi < bi)) { best = ov; bi = oi; }
        }
        if (l == 0) {
            unsigned int pb = __float_as_uint(best);
            atomicAdd(&lh[bucket_of(pb)], 1u);
            unsigned int cb = pb;
            if (bi == labels[row]) cb |= 0x80000000u;
            conf[row] = __uint_as_float(cb);
        }
    }
    __syncthreads();
    for (int i = threadIdx.x; i < NH; i += 256) {
        unsigned int c = lh[i];
        if (c) atomicAdd(&hist[i], c);
    }
    // ---- last block does the scan + boundary search ----
    __threadfence();
    __shared__ unsigned int isLast;
    if (threadIdx.x == 0) isLast = (atomicAdd(ticket, 1u) == gridDim.x - 1u) ? 1u : 0u;
    __syncthreads();
    if (!isLast) return;

    __shared__ unsigned int sp[NH];
    __shared__ unsigned int s[256];
    int tid = threadIdx.x;
    unsigned int loc[9];
    unsigned int tot = 0;
    int base = tid * 9;
    #pragma unroll
    for (int k = 0; k < 9; k++) {
        int idx = base + k;
        unsigned int v = (idx < NH) ? atomicAdd(&hist[idx], 0u) : 0u;  // coherent read
        loc[k] = tot; tot += v;
    }
    s[tid] = tot; __syncthreads();
    for (int off = 1; off < 256; off <<= 1) {
        unsigned int v = (tid >= off) ? s[tid - off] : 0u;
        __syncthreads();
        s[tid] += v;
        __syncthreads();
    }
    unsigned int excl = s[tid] - tot;
    #pragma unroll
    for (int k = 0; k < 9; k++) {
        int idx = base + k;
        if (idx < NH) { unsigned int e = excl + loc[k]; prefix[idx] = e; sp[idx] = e; }
    }
    __syncthreads();
    if (tid < NB) {
        unsigned int r = (unsigned int)(tid + 1) * W;
        int lo = 0, hi = NH - 1;
        while (lo < hi) {
            int mid = (lo + hi + 1) >> 1;
            if (sp[mid] <= r) lo = mid; else hi = mid - 1;
        }
        bnd[tid] = (sp[lo] < r) ? (unsigned int)lo : 0xFFFFFFFFu;
    }
}

// ---------- K2: single conf pass — bin accum + boundary sub-sums ----------
__global__ __launch_bounds__(256) void k2_accum(const float* __restrict__ conf,
                                                const unsigned int* __restrict__ prefix,
                                                const unsigned int* __restrict__ bnd,
                                                unsigned int* __restrict__ subcnt,
                                                float* __restrict__ subc,
                                                float* __restrict__ suba,
                                                double* __restrict__ bins) {
    __shared__ unsigned int ptab[NH];           // prefix | (slot+1)<<24
    __shared__ float sc[4][NBINS], sa[4][NBINS];
    for (int i = threadIdx.x; i < NH; i += 256) ptab[i] = prefix[i];
    for (int i = threadIdx.x; i < 4 * NBINS; i += 256) {
        (&sc[0][0])[i] = 0.f; (&sa[0][0])[i] = 0.f;
    }
    __syncthreads();
    if (threadIdx.x < NB) {
        unsigned int b = bnd[threadIdx.x];
        if (b != 0xFFFFFFFFu) ptab[b] |= (unsigned int)(threadIdx.x + 1) << 24;
    }
    __syncthreads();
    int wid = threadIdx.x >> 6;
    const uint4* c4 = reinterpret_cast<const uint4*>(conf);
    int stride = gridDim.x * 256;
    for (int i = blockIdx.x * 256 + threadIdx.x; i < NROWS / 4; i += stride) {
        uint4 q = c4[i];
        unsigned int bs[4] = { q.x, q.y, q.z, q.w };
        #pragma unroll
        for (int j = 0; j < 4; j++) {
            unsigned int raw = bs[j];
            float a = (float)(raw >> 31);
            unsigned int bits = raw & 0x7FFFFFFFu;
            float c = __uint_as_float(bits);
            unsigned int e = ptab[bucket_of(bits)];
            unsigned int s = e >> 24;
            if (s == 0u) {
                unsigned int bin = (e & 0xFFFFFFu) / W;
                atomicAdd(&sc[wid][bin], c); atomicAdd(&sa[wid][bin], a);
            } else {
                unsigned int idx = (s - 1u) * SUBN + (bits & 0xFFFu);
                atomicAdd(&subcnt[idx], 1u);
                atomicAdd(&subc[idx], c);
                atomicAdd(&suba[idx], a);
            }
        }
    }
    __syncthreads();
    if (threadIdx.x < NBINS) {
        float tc = sc[0][threadIdx.x] + sc[1][threadIdx.x] + sc[2][threadIdx.x] + sc[3][threadIdx.x];
        float ta = sa[0][threadIdx.x] + sa[1][threadIdx.x] + sa[2][threadIdx.x] + sa[3][threadIdx.x];
        atomicAdd(&bins[threadIdx.x],         (double)tc);
        atomicAdd(&bins[NBINS + threadIdx.x], (double)ta);
    }
}

// ---------- K3: one block — wave-parallel boundary split + finalize --------
__global__ __launch_bounds__(1024) void k3_final(const unsigned int* __restrict__ prefix,
                                                 const unsigned int* __restrict__ bnd,
                                                 const unsigned int* __restrict__ subcnt,
                                                 const float* __restrict__ subc,
                                                 const float* __restrict__ suba,
                                                 const double* __restrict__ bins,
                                                 float* __restrict__ out) {
    __shared__ float s_lowc[NB], s_lowa[NB], s_totc[NB], s_tota[NB];
    if (threadIdx.x < NB) {
        s_lowc[threadIdx.x] = 0.f; s_lowa[threadIdx.x] = 0.f;
        s_totc[threadIdx.x] = 0.f; s_tota[threadIdx.x] = 0.f;
    }
    __syncthreads();
    int wave = threadIdx.x >> 6;
    int lane = threadIdx.x & 63;
    for (int slot = wave; slot < NB; slot += 16) {
        unsigned int b = bnd[slot];
        if (b == 0xFFFFFFFFu) continue;           // boundary falls between buckets
        unsigned int offset = (unsigned int)(slot + 1) * W - prefix[b];
        const unsigned int* cnt = subcnt + slot * SUBN;
        const float* cc = subc + slot * SUBN;
        const float* aa = suba + slot * SUBN;
        int f0 = lane * 64;
        unsigned int lcnt = 0; float lc = 0.f, la = 0.f;
        for (int k = 0; k < 64; k++) { lcnt += cnt[f0 + k]; lc += cc[f0 + k]; la += aa[f0 + k]; }
        // exclusive scan of lcnt across the wave
        unsigned int run = lcnt;
        for (int off = 1; off < 64; off <<= 1) {
            unsigned int n = __shfl_up(run, off);
            if (lane >= off) run += n;
        }
        unsigned int excl = run - lcnt;
        // locate crossing fine-value F
        int haveF = (excl < offset && offset <= excl + lcnt) ? 1 : 0;
        unsigned int F = 0, BL = 0, BM = 1; float cF = 0.f, aF = 0.f;
        if (haveF) {
            unsigned int ex = excl;
            for (int k = 0; k < 64; k++) {
                unsigned int cv = cnt[f0 + k];
                if (ex < offset && offset <= ex + cv) { F = f0 + k; BL = offset - ex; BM = cv; cF = cc[f0 + k]; aF = aa[f0 + k]; break; }
                ex += cv;
            }
        }
        unsigned long long m = __ballot(haveF);
        int src = (int)(__ffsll((long long)m) - 1);
        F  = (unsigned int)__shfl((int)F,  src);
        BL = (unsigned int)__shfl((int)BL, src);
        BM = (unsigned int)__shfl((int)BM, src);
        cF = __shfl(cF, src);
        aF = __shfl(aF, src);
        // sums strictly below F
        float bc = 0.f, ba = 0.f;
        for (int k = 0; k < 64; k++) {
            if ((unsigned int)(f0 + k) < F) { bc += cc[f0 + k]; ba += aa[f0 + k]; }
        }
        #pragma unroll
        for (int off = 32; off >= 1; off >>= 1) {
            bc += __shfl_xor(bc, off); ba += __shfl_xor(ba, off);
            lc += __shfl_xor(lc, off); la += __shfl_xor(la, off);
        }
        if (lane == 0) {
            float fr = (float)BL / (float)BM;
            s_lowc[slot] = bc + fr * cF;  s_lowa[slot] = ba + fr * aF;
            s_totc[slot] = lc;            s_tota[slot] = la;
        }
    }
    __syncthreads();
    if (threadIdx.x == 0) {
        double bc_[NBINS], ba_[NBINS];
        for (int b = 0; b < NBINS; b++) { bc_[b] = bins[b]; ba_[b] = bins[NBINS + b]; }
        for (int t = 0; t < NB; t++) {
            bc_[t]     += (double)s_lowc[t];
            ba_[t]     += (double)s_lowa[t];
            bc_[t + 1] += (double)(s_totc[t] - s_lowc[t]);
            ba_[t + 1] += (double)(s_tota[t] - s_lowa[t]);
        }
        double ece = 0.0;
        for (int b = 0; b < NBINS; b++) {
            double avc = bc_[b] / (double)W;
            double ava = ba_[b] / (double)W;
            ece += fabs(avc - ava);
            out[1 + b] = (float)ava;
        }
        out[0] = (float)(ece * ((double)W / (double)NROWS));
    }
}

extern "C" void kernel_launch(void* const* d_in, const int* in_sizes, int n_in,
                              void* d_out, int out_size, void* d_ws, size_t ws_size,
                              hipStream_t stream) {
    const float* x      = (const float*)d_in[0];
    const int*   labels = (const int*)d_in[1];
    float*       out    = (float*)d_out;
    unsigned int* wd    = (unsigned int*)d_ws;

    unsigned int* hist    = wd + HIST_DW;
    unsigned int* subcnt  = wd + SUBCNT_DW;
    float*        subc    = (float*)(wd + SUBC_DW);
    float*        suba    = (float*)(wd + SUBA_DW);
    double*       bins    = (double*)(wd + BINS_DW);
    unsigned int* ticket  = wd + TICKET_DW;
    unsigned int* prefix  = wd + PREF_DW;
    unsigned int* bnd     = wd + BND_DW;
    float*        conf    = (float*)(wd + CONF_DW);

    k0_zero  <<<(ZERO_DW + 255) / 256, 256, 0, stream>>>(wd);
    k1_rowmax<<<2048, 256, 0, stream>>>(x, labels, conf, hist, prefix, bnd, ticket);
    k2_accum <<<512, 256, 0, stream>>>(conf, prefix, bnd, subcnt, subc, suba, bins);
    k3_final <<<1, 1024, 0, stream>>>(prefix, bnd, subcnt, subc, suba, bins, out);
}

// Round 6
// 151.150 us; speedup vs baseline: 3.0591x; 3.0591x over previous
//
#include <hip/hip_runtime.h>
#include <hip/hip_bf16.h>
#include <math.h>
#include <stdint.h>

#define NROWS 1000000
#define NCOLS 100
#define NBINS 20
#define NB    19       // bin boundaries
#define W     50000u   // rows per bin
#define NH    2049     // buckets: 0 = catch-all (<0.5), 1..2048 = [0.5,1) in 2^-12 steps

// ---------- ws layout (dword offsets) ----------
#define HIST_DW 0u       // len 2052
#define BINS_DW 2052u    // len 80 dw = 40 doubles (byte 8208, 8-aligned)
#define ZERO_DW 2132u    // hist+bins zeroed inside k1
#define CONF_DW 2136u    // len 1000000 (byte 8544 = 534*16, 16B-aligned); sign bit = accuracy

__device__ __forceinline__ unsigned int bucket_of(unsigned int bits) {
    // bits = positive-f32 pattern. conf < 0.5 -> 0 (catch-all).
    if (bits < 0x3F000000u) return 0u;
    unsigned int t = (bits >> 12) - 258048u + 1u;   // 1..2048 for [0.5,1)
    return t > 2048u ? 2048u : t;
}

// ---------- K1: wave-cooperative row max/argmax; acc packed in sign bit ----
// (round-4 proven form: NO fences, NO tickets, NO in-kernel histogram)
__global__ __launch_bounds__(256) void k1_rowmax(const float* __restrict__ x,
                                                 const int* __restrict__ labels,
                                                 float* __restrict__ conf,
                                                 unsigned int* __restrict__ zero_region) {
    int gtid = blockIdx.x * 256 + threadIdx.x;
    if (gtid < (int)ZERO_DW) zero_region[gtid] = 0u;   // hist + bins

    int wave = gtid >> 6;
    int lane = threadIdx.x & 63;
    int half = lane >> 5;
    int l    = lane & 31;
    int nwaves = (gridDim.x * 256) >> 6;

    for (int rp = wave; rp < NROWS / 2; rp += nwaves) {
        int row = rp * 2 + half;
        const float4* r4 = reinterpret_cast<const float4*>(x + (size_t)row * NCOLS);
        float best = -1.0f;
        int bi = 999;
        if (l < 25) {
            float4 v = r4[l];
            best = v.x; bi = 4 * l;
            if (v.y > best) { best = v.y; bi = 4 * l + 1; }
            if (v.z > best) { best = v.z; bi = 4 * l + 2; }
            if (v.w > best) { best = v.w; bi = 4 * l + 3; }
        }
        #pragma unroll
        for (int mask = 16; mask >= 1; mask >>= 1) {
            float ov = __shfl_xor(best, mask);
            int   oi = __shfl_xor(bi,   mask);
            if (ov > best || (ov == best && oi < bi)) { best = ov; bi = oi; }
        }
        if (l == 0) {
            unsigned int cb = __float_as_uint(best);
            if (bi == labels[row]) cb |= 0x80000000u;
            conf[row] = __uint_as_float(cb);
        }
    }
}

// ---------- K2: 2049-bucket histogram, per-block LDS ----------
__global__ __launch_bounds__(512) void k2_hist(const float* __restrict__ conf,
                                               unsigned int* __restrict__ hist) {
    __shared__ unsigned int lh[NH];
    for (int i = threadIdx.x; i < NH; i += 512) lh[i] = 0u;
    __syncthreads();
    const uint4* c4 = reinterpret_cast<const uint4*>(conf);
    int stride = gridDim.x * 512;
    for (int i = blockIdx.x * 512 + threadIdx.x; i < NROWS / 4; i += stride) {
        uint4 v = c4[i];
        atomicAdd(&lh[bucket_of(v.x & 0x7FFFFFFFu)], 1u);
        atomicAdd(&lh[bucket_of(v.y & 0x7FFFFFFFu)], 1u);
        atomicAdd(&lh[bucket_of(v.z & 0x7FFFFFFFu)], 1u);
        atomicAdd(&lh[bucket_of(v.w & 0x7FFFFFFFu)], 1u);
    }
    __syncthreads();
    for (int i = threadIdx.x; i < NH; i += 512) {
        unsigned int c = lh[i];
        if (c) atomicAdd(&hist[i], c);
    }
}

// ---------- K3: per-block redundant scan+bounds, then split-accumulate ----
// Each block: scan hist -> prefix in LDS, binary-search the 19 boundary
// buckets, compute their split fractions, then stream conf once applying
// fractional bucket splits directly into per-wave LDS bins.
__global__ __launch_bounds__(256) void k3_accum(const float* __restrict__ conf,
                                                const unsigned int* __restrict__ hist,
                                                double* __restrict__ bins) {
    __shared__ unsigned int ptab[NH];   // prefix, later |= (slot+1)<<24 on boundary buckets
    __shared__ unsigned int s[256];
    __shared__ unsigned int bndS[NB];
    __shared__ float sFr[NB];
    __shared__ float sc[4][NBINS], sa[4][NBINS];
    int tid = threadIdx.x;

    // --- scan hist (2049) into ptab ---
    unsigned int loc[9];
    unsigned int tot = 0;
    int base = tid * 9;
    #pragma unroll
    for (int k = 0; k < 9; k++) {
        int idx = base + k;
        unsigned int v = (idx < NH) ? hist[idx] : 0u;
        loc[k] = tot; tot += v;
    }
    s[tid] = tot; __syncthreads();
    for (int off = 1; off < 256; off <<= 1) {
        unsigned int v = (tid >= off) ? s[tid - off] : 0u;
        __syncthreads();
        s[tid] += v;
        __syncthreads();
    }
    unsigned int excl = s[tid] - tot;
    #pragma unroll
    for (int k = 0; k < 9; k++) {
        int idx = base + k;
        if (idx < NH) ptab[idx] = excl + loc[k];
    }
    for (int i = tid; i < 4 * NBINS; i += 256) { (&sc[0][0])[i] = 0.f; (&sa[0][0])[i] = 0.f; }
    __syncthreads();

    // --- phase A: locate boundaries on the CLEAN prefix, save fr ---
    if (tid < NB) {
        unsigned int r = (unsigned int)(tid + 1) * W;
        int lo = 0, hi = NH - 1;
        while (lo < hi) {
            int mid = (lo + hi + 1) >> 1;
            if (ptab[mid] <= r) lo = mid; else hi = mid - 1;
        }
        unsigned int p = ptab[lo];
        if (p < r) {
            unsigned int cnt = ((lo + 1 < NH) ? ptab[lo + 1] : (unsigned int)NROWS) - p;
            bndS[tid] = (unsigned int)lo;
            sFr[tid]  = (float)(r - p) / (float)cnt;
        } else {
            bndS[tid] = 0xFFFFFFFFu;
        }
    }
    __syncthreads();
    // --- phase B: mark boundary buckets ---
    if (tid < NB && bndS[tid] != 0xFFFFFFFFu)
        ptab[bndS[tid]] |= (unsigned int)(tid + 1) << 24;
    __syncthreads();

    // --- main pass ---
    int wid = tid >> 6;
    const uint4* c4 = reinterpret_cast<const uint4*>(conf);
    int stride = gridDim.x * 256;
    for (int i = blockIdx.x * 256 + tid; i < NROWS / 4; i += stride) {
        uint4 q = c4[i];
        unsigned int bs[4] = { q.x, q.y, q.z, q.w };
        #pragma unroll
        for (int j = 0; j < 4; j++) {
            unsigned int raw = bs[j];
            float a = (float)(raw >> 31);
            unsigned int bits = raw & 0x7FFFFFFFu;
            float c = __uint_as_float(bits);
            unsigned int e = ptab[bucket_of(bits)];
            unsigned int t = e >> 24;
            if (t == 0u) {
                unsigned int bin = (e & 0xFFFFFFu) / W;
                atomicAdd(&sc[wid][bin], c); atomicAdd(&sa[wid][bin], a);
            } else {
                float fr = sFr[t - 1];
                atomicAdd(&sc[wid][t - 1], c * fr);
                atomicAdd(&sc[wid][t],     c * (1.f - fr));
                atomicAdd(&sa[wid][t - 1], a * fr);
                atomicAdd(&sa[wid][t],     a * (1.f - fr));
            }
        }
    }
    __syncthreads();
    if (tid < NBINS) {
        float tc = sc[0][tid] + sc[1][tid] + sc[2][tid] + sc[3][tid];
        float ta = sa[0][tid] + sa[1][tid] + sa[2][tid] + sa[3][tid];
        atomicAdd(&bins[tid],         (double)tc);
        atomicAdd(&bins[NBINS + tid], (double)ta);
    }
}

// ---------- K4: finalize ----------
__global__ __launch_bounds__(64) void k4_final(const double* __restrict__ bins,
                                               float* __restrict__ out) {
    if (threadIdx.x == 0) {
        double ece = 0.0;
        for (int b = 0; b < NBINS; b++) {
            double avc = bins[b] / (double)W;
            double ava = bins[NBINS + b] / (double)W;
            ece += fabs(avc - ava);
            out[1 + b] = (float)ava;
        }
        out[0] = (float)(ece * ((double)W / (double)NROWS));
    }
}

extern "C" void kernel_launch(void* const* d_in, const int* in_sizes, int n_in,
                              void* d_out, int out_size, void* d_ws, size_t ws_size,
                              hipStream_t stream) {
    const float* x      = (const float*)d_in[0];
    const int*   labels = (const int*)d_in[1];
    float*       out    = (float*)d_out;
    unsigned int* wd    = (unsigned int*)d_ws;

    unsigned int* hist = wd + HIST_DW;
    double*       bins = (double*)(wd + BINS_DW);
    float*        conf = (float*)(wd + CONF_DW);

    k1_rowmax<<<2048, 256, 0, stream>>>(x, labels, conf, wd);
    k2_hist  <<<128, 512, 0, stream>>>(conf, hist);
    k3_accum <<<512, 256, 0, stream>>>(conf, hist, bins);
    k4_final <<<1, 64, 0, stream>>>(bins, out);
}